// Round 6
// baseline (415.198 us; speedup 1.0000x reference)
//
#include <hip/hip_runtime.h>
#include <stdint.h>

typedef float f4 __attribute__((ext_vector_type(4)));

__device__ __forceinline__ double dot4d(f4 a, f4 b) {
    return (double)a.x * (double)b.x + (double)a.y * (double)b.y
         + (double)a.z * (double)b.z + (double)a.w * (double)b.w;
}

// ---------------------------------------------------------------------------
// One block per frame, 1024 threads. Compile-time shape.
// Phase 1: scores — 64 16-lane groups x exactly T/64 rows (uniform, no tail),
//          4 independent f64 accumulators, pre_w staged in LDS.
// Phase 2: GEMV logits (f64) + rank-select (value desc, index asc)
//          == stable top-K of argsort(-softmax); softmax monotonic -> skipped.
// Phase 3: bitmask+popcount compaction -> ascending token order in sel[].
// Phase 4: gather in FLAT f4-element space: dst element e <- row sel[e/N4],
//          col e%N4. 1% imbalance, fully coalesced dst, nontemporal stores.
// ---------------------------------------------------------------------------
template <int T, int D, int K>
__global__ __launch_bounds__(1024)
void fused_v2_kernel(const float* __restrict__ x,
                     const float* __restrict__ pre_w,
                     const float* __restrict__ pre_b,
                     const float* __restrict__ W,
                     const float* __restrict__ bias,
                     float* __restrict__ out) {
    constexpr int N4   = D / 4;        // 352 f4 per row
    constexpr int NJ   = N4 / 16;      // 22 iters per 16-lane group row
    constexpr int NGRP = 64;           // 16-lane groups per block
    constexpr int RPG  = T / NGRP;     // 9 rows per group (uniform)
    constexpr int NW   = (T + 31) / 32;
    constexpr int E    = K * N4;       // 50688 f4 elements per frame
    constexpr int FULL = E / 1024;     // 49 full passes
    constexpr int REM  = E - FULL * 1024;  // 512 tail elements

    __shared__ f4       w_sh[N4];
    __shared__ double   s_sh[T];
    __shared__ double   lg[T];
    __shared__ unsigned flags[NW];
    __shared__ int      sel[K];

    const int f   = blockIdx.x;
    const int tid = threadIdx.x;
    const int sub = tid & 15;          // lane within 16-lane group
    const int gid = tid >> 4;          // group id 0..63

    for (int i = tid; i < N4; i += 1024) w_sh[i] = ((const f4*)pre_w)[i];
    if (tid < NW) flags[tid] = 0u;
    __syncthreads();

    // ---------------- Phase 1: per-token scores ----------------
    const double pb = (double)pre_b[0];
    for (int m = 0; m < RPG; ++m) {
        const int r = gid + NGRP * m;
        const f4* xr = (const f4*)(x + ((size_t)f * T + r) * D);
        double a[4] = {0, 0, 0, 0};
        #pragma unroll
        for (int j = 0; j < NJ; ++j)
            a[j & 3] += dot4d(xr[sub + 16 * j], w_sh[sub + 16 * j]);
        double s = (a[0] + a[1]) + (a[2] + a[3]);
        s += __shfl_down(s, 8, 16);
        s += __shfl_down(s, 4, 16);
        s += __shfl_down(s, 2, 16);
        s += __shfl_down(s, 1, 16);
        if (sub == 0) s_sh[r] = s + pb;
    }
    __syncthreads();

    // ---------------- Phase 2: GEMV logits + rank-select ----------------
    if (tid < T) {
        const float* Wc = W + tid;
        double acc[8] = {0, 0, 0, 0, 0, 0, 0, 0};
        for (int tp = 0; tp < T; tp += 8) {
            #pragma unroll
            for (int u = 0; u < 8; ++u)
                acc[u] += s_sh[tp + u] * (double)Wc[(size_t)(tp + u) * T];
        }
        double r01 = (acc[0] + acc[1]) + (acc[2] + acc[3]);
        double r23 = (acc[4] + acc[5]) + (acc[6] + acc[7]);
        lg[tid] = (r01 + r23) + (double)bias[tid];
    }
    __syncthreads();

    if (tid < T) {
        const double v = lg[tid];
        int rank = 0;
        #pragma unroll 8
        for (int tp = 0; tp < T; ++tp) {
            double u = lg[tp];
            rank += (u > v) || (u == v && tp < tid);
        }
        if (rank < K) atomicOr(&flags[tid >> 5], 1u << (tid & 31));
    }
    __syncthreads();

    // ---------------- Phase 3: ascending compaction ----------------
    if (tid < T) {
        if ((flags[tid >> 5] >> (tid & 31)) & 1u) {
            int pos = __popc(flags[tid >> 5] & ((1u << (tid & 31)) - 1u));
            for (int u2 = 0; u2 < (tid >> 5); ++u2) pos += __popc(flags[u2]);
            sel[pos] = tid;
        }
    }
    __syncthreads();

    // ---------------- Phase 4: flat-element gather ----------------
    const f4* xf  = (const f4*)(x + (size_t)f * T * D);
    f4*       dsf = (f4*)(out + (size_t)f * K * D);
    #pragma unroll 4
    for (int i = 0; i < FULL; ++i) {
        const int e   = tid + 1024 * i;
        const int row = e / N4;              // compile-time const divisor
        const int col = e - row * N4;
        f4 v = xf[(size_t)sel[row] * N4 + col];
        __builtin_nontemporal_store(v, &dsf[e]);
    }
    if (tid < REM) {
        const int e   = tid + 1024 * FULL;
        const int row = e / N4;
        const int col = e - row * N4;
        f4 v = xf[(size_t)sel[row] * N4 + col];
        __builtin_nontemporal_store(v, &dsf[e]);
    }
}

// ---------------------------------------------------------------------------
// Generic fallback (runtime shape) — proven-correct fused kernel from R2-R5.
// ---------------------------------------------------------------------------
__global__ __launch_bounds__(1024)
void fused_select_kernel(const float* __restrict__ x,
                         const float* __restrict__ pre_w,
                         const float* __restrict__ pre_b,
                         const float* __restrict__ W,
                         const float* __restrict__ bias,
                         float* __restrict__ out,
                         int T, int D, int K) {
    __shared__ double   s_sh[1024];
    __shared__ double   lg[1024];
    __shared__ unsigned flags[32];
    __shared__ int      sel[576];

    const int f    = blockIdx.x;
    const int tid  = threadIdx.x;
    const int wave = tid >> 6;
    const int lane = tid & 63;
    const int nw   = blockDim.x >> 6;
    const int n4   = D >> 2;

    const f4* wv = (const f4*)pre_w;
    for (int t = wave; t < T; t += nw) {
        const f4* xr = (const f4*)(x + ((size_t)f * T + t) * D);
        double acc = 0.0;
        for (int p = lane; p < n4; p += 64) acc += dot4d(xr[p], wv[p]);
#pragma unroll
        for (int off = 32; off > 0; off >>= 1) acc += __shfl_down(acc, off);
        if (lane == 0) s_sh[t] = acc + (double)pre_b[0];
    }
    if (tid < 32) flags[tid] = 0u;
    __syncthreads();

    if (tid < T) {
        const float* Wc = W + tid;
        double a0 = 0, a1 = 0, a2 = 0, a3 = 0;
        int tp = 0;
        for (; tp + 4 <= T; tp += 4) {
            a0 += s_sh[tp + 0] * (double)Wc[(size_t)(tp + 0) * T];
            a1 += s_sh[tp + 1] * (double)Wc[(size_t)(tp + 1) * T];
            a2 += s_sh[tp + 2] * (double)Wc[(size_t)(tp + 2) * T];
            a3 += s_sh[tp + 3] * (double)Wc[(size_t)(tp + 3) * T];
        }
        for (; tp < T; ++tp) a0 += s_sh[tp] * (double)Wc[(size_t)tp * T];
        lg[tid] = ((a0 + a1) + (a2 + a3)) + (double)bias[tid];
    }
    __syncthreads();
    if (tid < T) {
        const double v = lg[tid];
        int rank = 0;
        for (int tp = 0; tp < T; ++tp) {
            double u = lg[tp];
            rank += (u > v) || (u == v && tp < tid);
        }
        if (rank < K) atomicOr(&flags[tid >> 5], 1u << (tid & 31));
    }
    __syncthreads();
    if (tid < T) {
        if ((flags[tid >> 5] >> (tid & 31)) & 1u) {
            int pos = __popc(flags[tid >> 5] & ((1u << (tid & 31)) - 1u));
            for (int u2 = 0; u2 < (tid >> 5); ++u2) pos += __popc(flags[u2]);
            sel[pos] = tid;
        }
    }
    __syncthreads();
    for (int k2 = wave; k2 < K; k2 += nw) {
        int t = sel[k2];
        const f4* src = (const f4*)(x + ((size_t)f * T + t) * D);
        f4*       dst = (f4*)(out + ((size_t)f * K + k2) * D);
        for (int p = lane; p < n4; p += 64)
            __builtin_nontemporal_store(src[p], &dst[p]);
    }
}

// ---------------------------------------------------------------------------
extern "C" void kernel_launch(void* const* d_in, const int* in_sizes, int n_in,
                              void* d_out, int out_size, void* d_ws, size_t ws_size,
                              hipStream_t stream) {
    const float* x     = (const float*)d_in[0];
    const float* pre_w = (const float*)d_in[1];
    const float* pre_b = (const float*)d_in[2];
    const float* W     = (const float*)d_in[3];
    const float* bias  = (const float*)d_in[4];
    float* outp = (float*)d_out;

    const int D = in_sizes[1];          // pre_w is [1, D]
    const int T = in_sizes[4];          // trans_bias is [T]
    const int F = in_sizes[0] / (T * D);
    const int K = out_size / (F * D);

    if (T == 576 && D == 1408 && K == 144) {
        fused_v2_kernel<576, 1408, 144><<<F, 1024, 0, stream>>>(
            x, pre_w, pre_b, W, bias, outp);
    } else {
        fused_select_kernel<<<F, 1024, 0, stream>>>(x, pre_w, pre_b, W, bias,
                                                    outp, T, D, K);
    }
}

// Round 7
// 264.056 us; speedup vs baseline: 1.5724x; 1.5724x over previous
//
#include <hip/hip_runtime.h>
#include <stdint.h>

typedef float f4 __attribute__((ext_vector_type(4)));

__device__ __forceinline__ double dot4d(f4 a, f4 b) {
    return (double)a.x * (double)b.x + (double)a.y * (double)b.y
         + (double)a.z * (double)b.z + (double)a.w * (double)b.w;
}

// ---------------------------------------------------------------------------
// One block per frame, 1024 threads (16 waves). Compile-time shape.
// Phase 1: scores — 8-lane group per token row (R4-proven form).
// Phase 2: GEMV logits (f64) + rank-select (value desc, index asc)
//          == stable top-K of argsort(-softmax); softmax monotonic -> skipped.
// Phase 3: bitmask+popcount compaction -> ascending token order in sel[].
// Phase 4: gather — wave-per-row, 16 waves x exactly K/16 rows (perfectly
//          balanced), 5 unrolled 64-lane f4 iters + 32-lane tail per row,
//          nontemporal stores. (R6's flat-element form regressed: per-element
//          LDS-dependent addressing; this keeps one LDS broadcast per row.)
// ---------------------------------------------------------------------------
template <int T, int D, int K>
__global__ __launch_bounds__(1024)
void fused_v3_kernel(const float* __restrict__ x,
                     const float* __restrict__ pre_w,
                     const float* __restrict__ pre_b,
                     const float* __restrict__ W,
                     const float* __restrict__ bias,
                     float* __restrict__ out) {
    constexpr int N4 = D / 4;        // 352 f4 per row
    constexpr int NJ = N4 / 8;       // 44 iters per 8-lane group row
    constexpr int NG = 128;          // 8-lane groups per block
    constexpr int NW = (T + 31) / 32;
    constexpr int RFULL = N4 / 64;            // 5 full 64-lane passes per row
    constexpr int RREM  = N4 - RFULL * 64;    // 32 remaining f4

    __shared__ f4       w_sh[N4];
    __shared__ double   s_sh[T];
    __shared__ double   lg[T];
    __shared__ unsigned flags[NW];
    __shared__ int      sel[K];

    const int f    = blockIdx.x;
    const int tid  = threadIdx.x;
    const int sub  = tid & 7;        // lane within 8-lane group
    const int gid  = tid >> 3;       // group id 0..127
    const int wave = tid >> 6;       // wave id 0..15
    const int lane = tid & 63;

    for (int i = tid; i < N4; i += 1024) w_sh[i] = ((const f4*)pre_w)[i];
    if (tid < NW) flags[tid] = 0u;
    __syncthreads();

    // ---------------- Phase 1: per-token scores (R4-proven) ----------------
    const double pb = (double)pre_b[0];
    for (int r = gid; r < T; r += NG) {
        const f4* xr = (const f4*)(x + ((size_t)f * T + r) * D);
        double a0 = 0, a1 = 0, a2 = 0, a3 = 0;
        #pragma unroll 2
        for (int j = 0; j < NJ; j += 4) {
            f4 v0 = xr[sub + 8 * (j + 0)];
            f4 v1 = xr[sub + 8 * (j + 1)];
            f4 v2 = xr[sub + 8 * (j + 2)];
            f4 v3 = xr[sub + 8 * (j + 3)];
            f4 u0 = w_sh[sub + 8 * (j + 0)];
            f4 u1 = w_sh[sub + 8 * (j + 1)];
            f4 u2 = w_sh[sub + 8 * (j + 2)];
            f4 u3 = w_sh[sub + 8 * (j + 3)];
            a0 += dot4d(v0, u0);
            a1 += dot4d(v1, u1);
            a2 += dot4d(v2, u2);
            a3 += dot4d(v3, u3);
        }
        double a = (a0 + a1) + (a2 + a3);
        a += __shfl_down(a, 4, 8);
        a += __shfl_down(a, 2, 8);
        a += __shfl_down(a, 1, 8);
        if (sub == 0) s_sh[r] = a + pb;
    }
    __syncthreads();

    // ---------------- Phase 2: GEMV logits + rank-select ----------------
    if (tid < T) {
        const float* Wc = W + tid;
        double acc[8] = {0, 0, 0, 0, 0, 0, 0, 0};
        for (int tp = 0; tp < T; tp += 8) {
            #pragma unroll
            for (int u = 0; u < 8; ++u)
                acc[u] += s_sh[tp + u] * (double)Wc[(size_t)(tp + u) * T];
        }
        double r01 = (acc[0] + acc[1]) + (acc[2] + acc[3]);
        double r23 = (acc[4] + acc[5]) + (acc[6] + acc[7]);
        lg[tid] = (r01 + r23) + (double)bias[tid];
    }
    __syncthreads();

    if (tid < T) {
        const double v = lg[tid];
        int rank = 0;
        #pragma unroll 8
        for (int tp = 0; tp < T; ++tp) {
            double u = lg[tp];
            rank += (u > v) || (u == v && tp < tid);
        }
        if (rank < K) atomicOr(&flags[tid >> 5], 1u << (tid & 31));
    }
    __syncthreads();

    // ---------------- Phase 3: ascending compaction ----------------
    if (tid < T) {
        if ((flags[tid >> 5] >> (tid & 31)) & 1u) {
            int pos = __popc(flags[tid >> 5] & ((1u << (tid & 31)) - 1u));
            for (int u2 = 0; u2 < (tid >> 5); ++u2) pos += __popc(flags[u2]);
            sel[pos] = tid;
        }
    }
    __syncthreads();

    // ---------------- Phase 4: wave-per-row gather (balanced) ----------------
    for (int k2 = wave; k2 < K; k2 += 16) {   // exactly K/16 rows per wave
        const int t = sel[k2];
        const f4* src = (const f4*)(x + ((size_t)f * T + t) * D);
        f4*       dst = (f4*)(out + ((size_t)f * K + k2) * D);
        f4 v0 = src[lane + 64 * 0];
        f4 v1 = src[lane + 64 * 1];
        f4 v2 = src[lane + 64 * 2];
        f4 v3 = src[lane + 64 * 3];
        f4 v4 = src[lane + 64 * 4];
        __builtin_nontemporal_store(v0, &dst[lane + 64 * 0]);
        __builtin_nontemporal_store(v1, &dst[lane + 64 * 1]);
        __builtin_nontemporal_store(v2, &dst[lane + 64 * 2]);
        __builtin_nontemporal_store(v3, &dst[lane + 64 * 3]);
        __builtin_nontemporal_store(v4, &dst[lane + 64 * 4]);
        if (lane < RREM) {
            f4 v5 = src[lane + 64 * RFULL];
            __builtin_nontemporal_store(v5, &dst[lane + 64 * RFULL]);
        }
    }
}

// ---------------------------------------------------------------------------
// Generic fallback (runtime shape) — proven-correct fused kernel from R2-R5.
// ---------------------------------------------------------------------------
__global__ __launch_bounds__(1024)
void fused_select_kernel(const float* __restrict__ x,
                         const float* __restrict__ pre_w,
                         const float* __restrict__ pre_b,
                         const float* __restrict__ W,
                         const float* __restrict__ bias,
                         float* __restrict__ out,
                         int T, int D, int K) {
    __shared__ double   s_sh[1024];
    __shared__ double   lg[1024];
    __shared__ unsigned flags[32];
    __shared__ int      sel[576];

    const int f    = blockIdx.x;
    const int tid  = threadIdx.x;
    const int wave = tid >> 6;
    const int lane = tid & 63;
    const int nw   = blockDim.x >> 6;
    const int n4   = D >> 2;

    const f4* wv = (const f4*)pre_w;
    for (int t = wave; t < T; t += nw) {
        const f4* xr = (const f4*)(x + ((size_t)f * T + t) * D);
        double acc = 0.0;
        for (int p = lane; p < n4; p += 64) acc += dot4d(xr[p], wv[p]);
#pragma unroll
        for (int off = 32; off > 0; off >>= 1) acc += __shfl_down(acc, off);
        if (lane == 0) s_sh[t] = acc + (double)pre_b[0];
    }
    if (tid < 32) flags[tid] = 0u;
    __syncthreads();

    if (tid < T) {
        const float* Wc = W + tid;
        double a0 = 0, a1 = 0, a2 = 0, a3 = 0;
        int tp = 0;
        for (; tp + 4 <= T; tp += 4) {
            a0 += s_sh[tp + 0] * (double)Wc[(size_t)(tp + 0) * T];
            a1 += s_sh[tp + 1] * (double)Wc[(size_t)(tp + 1) * T];
            a2 += s_sh[tp + 2] * (double)Wc[(size_t)(tp + 2) * T];
            a3 += s_sh[tp + 3] * (double)Wc[(size_t)(tp + 3) * T];
        }
        for (; tp < T; ++tp) a0 += s_sh[tp] * (double)Wc[(size_t)tp * T];
        lg[tid] = ((a0 + a1) + (a2 + a3)) + (double)bias[tid];
    }
    __syncthreads();
    if (tid < T) {
        const double v = lg[tid];
        int rank = 0;
        for (int tp = 0; tp < T; ++tp) {
            double u = lg[tp];
            rank += (u > v) || (u == v && tp < tid);
        }
        if (rank < K) atomicOr(&flags[tid >> 5], 1u << (tid & 31));
    }
    __syncthreads();
    if (tid < T) {
        if ((flags[tid >> 5] >> (tid & 31)) & 1u) {
            int pos = __popc(flags[tid >> 5] & ((1u << (tid & 31)) - 1u));
            for (int u2 = 0; u2 < (tid >> 5); ++u2) pos += __popc(flags[u2]);
            sel[pos] = tid;
        }
    }
    __syncthreads();
    for (int k2 = wave; k2 < K; k2 += nw) {
        int t = sel[k2];
        const f4* src = (const f4*)(x + ((size_t)f * T + t) * D);
        f4*       dst = (f4*)(out + ((size_t)f * K + k2) * D);
        for (int p = lane; p < n4; p += 64)
            __builtin_nontemporal_store(src[p], &dst[p]);
    }
}

// ---------------------------------------------------------------------------
extern "C" void kernel_launch(void* const* d_in, const int* in_sizes, int n_in,
                              void* d_out, int out_size, void* d_ws, size_t ws_size,
                              hipStream_t stream) {
    const float* x     = (const float*)d_in[0];
    const float* pre_w = (const float*)d_in[1];
    const float* pre_b = (const float*)d_in[2];
    const float* W     = (const float*)d_in[3];
    const float* bias  = (const float*)d_in[4];
    float* outp = (float*)d_out;

    const int D = in_sizes[1];          // pre_w is [1, D]
    const int T = in_sizes[4];          // trans_bias is [T]
    const int F = in_sizes[0] / (T * D);
    const int K = out_size / (F * D);

    if (T == 576 && D == 1408 && K == 144 && (K % 16 == 0)) {
        fused_v3_kernel<576, 1408, 144><<<F, 1024, 0, stream>>>(
            x, pre_w, pre_b, W, bias, outp);
    } else {
        fused_select_kernel<<<F, 1024, 0, stream>>>(x, pre_w, pre_b, W, bias,
                                                    outp, T, D, K);
    }
}

// Round 8
// 253.682 us; speedup vs baseline: 1.6367x; 1.0409x over previous
//
#include <hip/hip_runtime.h>
#include <stdint.h>

typedef float f4 __attribute__((ext_vector_type(4)));

__device__ __forceinline__ double dot4d(f4 a, f4 b) {
    return (double)a.x * (double)b.x + (double)a.y * (double)b.y
         + (double)a.z * (double)b.z + (double)a.w * (double)b.w;
}

// ---------------------------------------------------------------------------
// One block per frame, 1024 threads (16 waves). Compile-time shape.
// Phase 1: scores — 16-lane group per token row, 64 groups x exactly T/64=9
//          rows (zero imbalance), 22 f4/lane/row, 4 independent f64 accs.
// Phase 2: GEMV logits (f64, 16 accs) + rank-select (value desc, index asc)
//          == stable top-K of argsort(-softmax); softmax monotonic -> skipped.
// Phase 3: bitmask+popcount compaction -> ascending token order in sel[].
// Phase 4: gather — wave-per-row, 16 waves x exactly K/16 rows, 5 unrolled
//          64-lane f4 iters + 32-lane tail per row, nontemporal stores.
// ---------------------------------------------------------------------------
template <int T, int D, int K>
__global__ __launch_bounds__(1024)
void fused_v4_kernel(const float* __restrict__ x,
                     const float* __restrict__ pre_w,
                     const float* __restrict__ pre_b,
                     const float* __restrict__ W,
                     const float* __restrict__ bias,
                     float* __restrict__ out) {
    constexpr int N4   = D / 4;          // 352 f4 per row
    constexpr int NJ   = N4 / 16;        // 22 f4 per lane per row
    constexpr int NGRP = 64;             // 16-lane groups per block
    constexpr int RPG  = T / NGRP;       // 9 rows per group (exact)
    constexpr int NW   = (T + 31) / 32;
    constexpr int RFULL = N4 / 64;           // 5 full 64-lane passes (gather)
    constexpr int RREM  = N4 - RFULL * 64;   // 32 remaining f4 (gather)
    static_assert(NJ == 22 && RPG * NGRP == T, "shape assumptions");

    __shared__ f4       w_sh[N4];
    __shared__ double   s_sh[T];
    __shared__ double   lg[T];
    __shared__ unsigned flags[NW];
    __shared__ int      sel[K];

    const int f    = blockIdx.x;
    const int tid  = threadIdx.x;
    const int sub  = tid & 15;           // lane within 16-lane group
    const int gid  = tid >> 4;           // group id 0..63
    const int wave = tid >> 6;           // wave id 0..15
    const int lane = tid & 63;

    for (int i = tid; i < N4; i += 1024) w_sh[i] = ((const f4*)pre_w)[i];
    if (tid < NW) flags[tid] = 0u;
    __syncthreads();

    // ---------------- Phase 1: per-token scores (exact balance) ----------------
    const double pb = (double)pre_b[0];
    for (int m = 0; m < RPG; ++m) {
        const int r = gid + NGRP * m;
        const f4* xr = (const f4*)(x + ((size_t)f * T + r) * D);
        double a0 = 0, a1 = 0, a2 = 0, a3 = 0;
        #pragma unroll 2
        for (int j = 0; j < 16; j += 4) {
            f4 v0 = xr[sub + 16 * (j + 0)];
            f4 v1 = xr[sub + 16 * (j + 1)];
            f4 v2 = xr[sub + 16 * (j + 2)];
            f4 v3 = xr[sub + 16 * (j + 3)];
            a0 += dot4d(v0, w_sh[sub + 16 * (j + 0)]);
            a1 += dot4d(v1, w_sh[sub + 16 * (j + 1)]);
            a2 += dot4d(v2, w_sh[sub + 16 * (j + 2)]);
            a3 += dot4d(v3, w_sh[sub + 16 * (j + 3)]);
        }
        {   // tail: j = 16..21 (6 f4)
            f4 v0 = xr[sub + 16 * 16];
            f4 v1 = xr[sub + 16 * 17];
            f4 v2 = xr[sub + 16 * 18];
            f4 v3 = xr[sub + 16 * 19];
            f4 v4 = xr[sub + 16 * 20];
            f4 v5 = xr[sub + 16 * 21];
            a0 += dot4d(v0, w_sh[sub + 16 * 16]);
            a1 += dot4d(v1, w_sh[sub + 16 * 17]);
            a2 += dot4d(v2, w_sh[sub + 16 * 18]);
            a3 += dot4d(v3, w_sh[sub + 16 * 19]);
            a0 += dot4d(v4, w_sh[sub + 16 * 20]);
            a1 += dot4d(v5, w_sh[sub + 16 * 21]);
        }
        double s = (a0 + a1) + (a2 + a3);
        s += __shfl_down(s, 8, 16);
        s += __shfl_down(s, 4, 16);
        s += __shfl_down(s, 2, 16);
        s += __shfl_down(s, 1, 16);
        if (sub == 0) s_sh[r] = s + pb;
    }
    __syncthreads();

    // ---------------- Phase 2: GEMV logits (16 accs) + rank-select ----------------
    if (tid < T) {
        const float* Wc = W + tid;
        double acc[16];
        #pragma unroll
        for (int u = 0; u < 16; ++u) acc[u] = 0.0;
        for (int tp = 0; tp < T; tp += 16) {
            #pragma unroll
            for (int u = 0; u < 16; ++u)
                acc[u] += s_sh[tp + u] * (double)Wc[(size_t)(tp + u) * T];
        }
        double r0 = (acc[0] + acc[1]) + (acc[2] + acc[3]);
        double r1 = (acc[4] + acc[5]) + (acc[6] + acc[7]);
        double r2 = (acc[8] + acc[9]) + (acc[10] + acc[11]);
        double r3 = (acc[12] + acc[13]) + (acc[14] + acc[15]);
        lg[tid] = ((r0 + r1) + (r2 + r3)) + (double)bias[tid];
    }
    __syncthreads();

    if (tid < T) {
        const double v = lg[tid];
        int rank = 0;
        #pragma unroll 8
        for (int tp = 0; tp < T; ++tp) {
            double u = lg[tp];
            rank += (u > v) || (u == v && tp < tid);
        }
        if (rank < K) atomicOr(&flags[tid >> 5], 1u << (tid & 31));
    }
    __syncthreads();

    // ---------------- Phase 3: ascending compaction ----------------
    if (tid < T) {
        if ((flags[tid >> 5] >> (tid & 31)) & 1u) {
            int pos = __popc(flags[tid >> 5] & ((1u << (tid & 31)) - 1u));
            for (int u2 = 0; u2 < (tid >> 5); ++u2) pos += __popc(flags[u2]);
            sel[pos] = tid;
        }
    }
    __syncthreads();

    // ---------------- Phase 4: wave-per-row gather (balanced) ----------------
    for (int k2 = wave; k2 < K; k2 += 16) {
        const int t = sel[k2];
        const f4* src = (const f4*)(x + ((size_t)f * T + t) * D);
        f4*       dst = (f4*)(out + ((size_t)f * K + k2) * D);
        f4 v0 = src[lane + 64 * 0];
        f4 v1 = src[lane + 64 * 1];
        f4 v2 = src[lane + 64 * 2];
        f4 v3 = src[lane + 64 * 3];
        f4 v4 = src[lane + 64 * 4];
        __builtin_nontemporal_store(v0, &dst[lane + 64 * 0]);
        __builtin_nontemporal_store(v1, &dst[lane + 64 * 1]);
        __builtin_nontemporal_store(v2, &dst[lane + 64 * 2]);
        __builtin_nontemporal_store(v3, &dst[lane + 64 * 3]);
        __builtin_nontemporal_store(v4, &dst[lane + 64 * 4]);
        if (lane < RREM) {
            f4 v5 = src[lane + 64 * RFULL];
            __builtin_nontemporal_store(v5, &dst[lane + 64 * RFULL]);
        }
    }
}

// ---------------------------------------------------------------------------
// Generic fallback (runtime shape) — proven-correct fused kernel from R2-R7.
// ---------------------------------------------------------------------------
__global__ __launch_bounds__(1024)
void fused_select_kernel(const float* __restrict__ x,
                         const float* __restrict__ pre_w,
                         const float* __restrict__ pre_b,
                         const float* __restrict__ W,
                         const float* __restrict__ bias,
                         float* __restrict__ out,
                         int T, int D, int K) {
    __shared__ double   s_sh[1024];
    __shared__ double   lg[1024];
    __shared__ unsigned flags[32];
    __shared__ int      sel[576];

    const int f    = blockIdx.x;
    const int tid  = threadIdx.x;
    const int wave = tid >> 6;
    const int lane = tid & 63;
    const int nw   = blockDim.x >> 6;
    const int n4   = D >> 2;

    const f4* wv = (const f4*)pre_w;
    for (int t = wave; t < T; t += nw) {
        const f4* xr = (const f4*)(x + ((size_t)f * T + t) * D);
        double acc = 0.0;
        for (int p = lane; p < n4; p += 64) acc += dot4d(xr[p], wv[p]);
#pragma unroll
        for (int off = 32; off > 0; off >>= 1) acc += __shfl_down(acc, off);
        if (lane == 0) s_sh[t] = acc + (double)pre_b[0];
    }
    if (tid < 32) flags[tid] = 0u;
    __syncthreads();

    if (tid < T) {
        const float* Wc = W + tid;
        double a0 = 0, a1 = 0, a2 = 0, a3 = 0;
        int tp = 0;
        for (; tp + 4 <= T; tp += 4) {
            a0 += s_sh[tp + 0] * (double)Wc[(size_t)(tp + 0) * T];
            a1 += s_sh[tp + 1] * (double)Wc[(size_t)(tp + 1) * T];
            a2 += s_sh[tp + 2] * (double)Wc[(size_t)(tp + 2) * T];
            a3 += s_sh[tp + 3] * (double)Wc[(size_t)(tp + 3) * T];
        }
        for (; tp < T; ++tp) a0 += s_sh[tp] * (double)Wc[(size_t)tp * T];
        lg[tid] = ((a0 + a1) + (a2 + a3)) + (double)bias[tid];
    }
    __syncthreads();
    if (tid < T) {
        const double v = lg[tid];
        int rank = 0;
        for (int tp = 0; tp < T; ++tp) {
            double u = lg[tp];
            rank += (u > v) || (u == v && tp < tid);
        }
        if (rank < K) atomicOr(&flags[tid >> 5], 1u << (tid & 31));
    }
    __syncthreads();
    if (tid < T) {
        if ((flags[tid >> 5] >> (tid & 31)) & 1u) {
            int pos = __popc(flags[tid >> 5] & ((1u << (tid & 31)) - 1u));
            for (int u2 = 0; u2 < (tid >> 5); ++u2) pos += __popc(flags[u2]);
            sel[pos] = tid;
        }
    }
    __syncthreads();
    for (int k2 = wave; k2 < K; k2 += nw) {
        int t = sel[k2];
        const f4* src = (const f4*)(x + ((size_t)f * T + t) * D);
        f4*       dst = (f4*)(out + ((size_t)f * K + k2) * D);
        for (int p = lane; p < n4; p += 64)
            __builtin_nontemporal_store(src[p], &dst[p]);
    }
}

// ---------------------------------------------------------------------------
extern "C" void kernel_launch(void* const* d_in, const int* in_sizes, int n_in,
                              void* d_out, int out_size, void* d_ws, size_t ws_size,
                              hipStream_t stream) {
    const float* x     = (const float*)d_in[0];
    const float* pre_w = (const float*)d_in[1];
    const float* pre_b = (const float*)d_in[2];
    const float* W     = (const float*)d_in[3];
    const float* bias  = (const float*)d_in[4];
    float* outp = (float*)d_out;

    const int D = in_sizes[1];          // pre_w is [1, D]
    const int T = in_sizes[4];          // trans_bias is [T]
    const int F = in_sizes[0] / (T * D);
    const int K = out_size / (F * D);

    if (T == 576 && D == 1408 && K == 144) {
        fused_v4_kernel<576, 1408, 144><<<F, 1024, 0, stream>>>(
            x, pre_w, pre_b, W, bias, outp);
    } else {
        fused_select_kernel<<<F, 1024, 0, stream>>>(x, pre_w, pre_b, W, bias,
                                                    outp, T, D, K);
    }
}